// Round 11
// baseline (2054.573 us; speedup 1.0000x reference)
//
#include <hip/hip_runtime.h>
#include <hip/hip_bf16.h>
#include <stdint.h>

#define NPT   16384   // N
#define BB    4
#define SS    1024    // NPOINT
#define KK    32      // NSAMPLE
#define RR    (BB*SS*KK) // 131072 rows
#define C1    67
#define O1    64
#define O3    128
#define EPSF  1e-5f
#define R2F   0.09f   // f32(0.09)
#define FT    1024    // FPS threads/block
#define BIGI  0x7fffffff

typedef float v2f __attribute__((ext_vector_type(2)));

#define REP8(M)  M(0) M(1) M(2) M(3) M(4) M(5) M(6) M(7)
#define REP8R(M) M(7) M(6) M(5) M(4) M(3) M(2) M(1) M(0)

// butterfly f32 max across a wave: 5 ds_swizzle levels + cross-32 shuffle
#define WMAX5(v) { \
    v = fmaxf(v, __int_as_float(__builtin_amdgcn_ds_swizzle(__float_as_int(v), 0x041F))); \
    v = fmaxf(v, __int_as_float(__builtin_amdgcn_ds_swizzle(__float_as_int(v), 0x081F))); \
    v = fmaxf(v, __int_as_float(__builtin_amdgcn_ds_swizzle(__float_as_int(v), 0x101F))); \
    v = fmaxf(v, __int_as_float(__builtin_amdgcn_ds_swizzle(__float_as_int(v), 0x201F))); \
    v = fmaxf(v, __int_as_float(__builtin_amdgcn_ds_swizzle(__float_as_int(v), 0x401F))); }

// ---------------- FPS: vector-IR packed phase 1, point-pairs (i, i+8) ---------
// R10 post-mortem: raw inline-asm v_pk_* (64-bit VOP3P operands) caused
// nondeterministic replay divergence AND a slowdown -- removed entirely.
// Same math as plain <2 x float> IR under fp contract(off): each lane is the
// exact rn sub/mul/mul/add/mul/add + fmin sequence (bitwise == reference, no
// FMA contraction). LLVM may select v_pk_{add,mul}_f32; worst case it
// scalarizes to R9's known-good codegen. Protocol (double-buffered single-cell
// atomics, z riding the argmin key) is byte-identical to the R9 passing kernel.
__global__ __launch_bounds__(FT)
__attribute__((amdgpu_waves_per_eu(4, 4)))
void k_fps(const float* __restrict__ xyz, int* __restrict__ fps_idx) {
#pragma clang fp contract(off)
    const int b = blockIdx.x;
    const int tid = threadIdx.x;
    const int lane = tid & 63;
    const float* xb = xyz + (size_t)b * 3 * NPT;

    __shared__ v2f sx2[8 * FT];                    // 64 KB: (x_n, x_{n+8192})
    __shared__ v2f sy2[8 * FT];                    // 64 KB
    __shared__ int s_M[2];                         // double-buffered max cell
    __shared__ unsigned long long s_wz[2];         // double-buffered (idx,z) cell

#define DECLV(p) v2f ZP##p, DP##p;
    REP8(DECLV)
#define INITV(p) { int n0 = (p) * FT + tid, n1 = ((p) + 8) * FT + tid; \
                   sx2[(p) * FT + tid] = (v2f){xb[n0], xb[n1]}; \
                   sy2[(p) * FT + tid] = (v2f){xb[NPT + n0], xb[NPT + n1]}; \
                   float z0 = xb[2 * NPT + n0], z1 = xb[2 * NPT + n1]; \
                   asm volatile("" : "+v"(z0), "+v"(z1)); \
                   ZP##p = (v2f){z0, z1}; \
                   DP##p = (v2f){1e10f, 1e10f}; }
    REP8(INITV)
    if (tid == 0) { s_M[0] = 0; s_M[1] = 0; s_wz[0] = ~0ull; s_wz[1] = ~0ull; }
    __syncthreads();                               // planes + cells visible

    const float* sxf = (const float*)sx2;
    const float* syf = (const float*)sy2;
    int p = 0;
    int far = 0;
    float cx = sxf[0], cy = syf[0], cz = xb[2 * NPT];   // point 0 = pair0 .x
    for (int it = 0; it < SS; ++it) {
        if (tid == 0) fps_idx[b * SS + it] = far;
        v2f cpx = (v2f){cx, cx};
        v2f cpy = (v2f){cy, cy};
        v2f cpz = (v2f){cz, cz};
        // exact reference arithmetic per lane: (dx*dx + dy*dy) + dz*dz, rn,
        // no contraction (pragma above)
#define UPDV(q) { v2f xp = sx2[(q) * FT + tid]; \
                  v2f yp = sy2[(q) * FT + tid]; \
                  v2f dx = xp - cpx; \
                  v2f dy = yp - cpy; \
                  v2f dz = ZP##q - cpz; \
                  v2f d = (dx * dx + dy * dy) + dz * dz; \
                  DP##q.x = fminf(DP##q.x, d.x); \
                  DP##q.y = fminf(DP##q.y, d.y); }
        REP8(UPDV)
        // depth-4 tree max of the 16 updated dists
        float t0 = fmaxf(fmaxf(DP0.x, DP0.y), fmaxf(DP1.x, DP1.y));
        float t1 = fmaxf(fmaxf(DP2.x, DP2.y), fmaxf(DP3.x, DP3.y));
        float t2 = fmaxf(fmaxf(DP4.x, DP4.y), fmaxf(DP5.x, DP5.y));
        float t3 = fmaxf(fmaxf(DP6.x, DP6.y), fmaxf(DP7.x, DP7.y));
        float tbd = fmaxf(fmaxf(t0, t1), fmaxf(t2, t3));   // thread max

        float bd = tbd;
        WMAX5(bd)
        bd = fmaxf(bd, __shfl_xor(bd, 32));                // wave max
        if (lane == 0) atomicMax(&s_M[p], __float_as_int(bd));
        __syncthreads();                  // barrier A: global max ready
        if (tid == 0) { s_M[p ^ 1] = 0; s_wz[p ^ 1] = ~0ull; }  // prep next iter
        float Mf = __int_as_float(s_M[p]);
        if (tbd == Mf) {                  // only threads holding the max scan
            int bn = BIGI; float zw = 0.0f;
            // descending n so the LOWEST matching index is assigned last
#define SCANY(q) { bool m = (DP##q.y == Mf); \
                   bn = m ? (((q) + 8) * FT + tid) : bn; \
                   zw = m ? ZP##q.y : zw; }
            REP8R(SCANY)
#define SCANX(q) { bool m = (DP##q.x == Mf); \
                   bn = m ? ((q) * FT + tid) : bn; \
                   zw = m ? ZP##q.x : zw; }
            REP8R(SCANX)
            atomicMin(&s_wz[p], ((unsigned long long)(unsigned)bn << 32) |
                                (unsigned long long)__float_as_uint(zw));
        }
        __syncthreads();                  // barrier B: winner ready
        unsigned long long wz = s_wz[p];
        far = (int)(wz >> 32);
        cz = __uint_as_float((unsigned)wz);
        int fi = far >> 10, ft2 = far & (FT - 1);
        int fidx = (((fi & 7) * FT + ft2) << 1) + (fi >> 3);
        cx = sxf[fidx];                   // uniform addr -> LDS broadcast
        cy = syf[fidx];
        p ^= 1;
    }
#undef DECLV
#undef INITV
#undef UPDV
#undef SCANY
#undef SCANX
}

// ---------------- gather new_xyz: output0 (B,3,S) + ws copy (b,s,3) ------------
__global__ void k_newxyz(const float* __restrict__ xyz, const int* __restrict__ fps_idx,
                         float* __restrict__ out0, float* __restrict__ nxyz) {
    int g = blockIdx.x * blockDim.x + threadIdx.x;
    if (g >= BB * SS) return;
    int b = g / SS, s = g % SS;
    int id = fps_idx[g];
    const float* xb = xyz + (size_t)b * 3 * NPT;
#pragma unroll
    for (int c = 0; c < 3; ++c) {
        float v = xb[c * NPT + id];
        out0[(size_t)b * 3 * SS + c * SS + s] = v;
        nxyz[g * 3 + c] = v;
    }
}

// ---------------- ball query: one wave per centroid, ballot ranking ------------
__global__ __launch_bounds__(256) void k_ball(const float* __restrict__ xyz,
                                              const float* __restrict__ nxyz,
                                              int* __restrict__ ballidx) {
    int wid = (blockIdx.x * 256 + threadIdx.x) >> 6;   // 0..4095
    int lane = threadIdx.x & 63;
    int b = wid >> 10;
    const float* xb = xyz + (size_t)b * 3 * NPT;
    float nx = nxyz[wid * 3], ny = nxyz[wid * 3 + 1], nz = nxyz[wid * 3 + 2];
    int* out = ballidx + (size_t)wid * KK;
    int cnt = 0;
    int first = -1;
    for (int base = 0; base < NPT; base += 64) {
        int n = base + lane;
        float dx = __fsub_rn(nx, xb[n]);
        float dy = __fsub_rn(ny, xb[NPT + n]);
        float dz = __fsub_rn(nz, xb[2 * NPT + n]);
        float d = __fadd_rn(__fadd_rn(__fmul_rn(dx, dx), __fmul_rn(dy, dy)),
                            __fmul_rn(dz, dz));
        bool hit = !(d > R2F);            // excluded iff sqr > r^2 (matches ref)
        unsigned long long mask = __ballot(hit);
        if (mask) {
            if (first < 0) first = base + __builtin_ctzll(mask);
            int rank = cnt + __popcll(mask & ((1ull << lane) - 1ull));
            if (hit && rank < KK) out[rank] = n;
            cnt += __popcll(mask);
        }
        if (cnt >= KK) break;
    }
    if (lane >= cnt && lane < KK) out[lane] = first;   // pad with first hit
}

// ---------------- transpose pts (B,64,N) -> ptsT (B,N,64) ----------------------
__global__ __launch_bounds__(256) void k_tr(const float* __restrict__ pts,
                                            float* __restrict__ ptsT) {
    __shared__ float t[64][65];
    int b = blockIdx.x >> 8, n0 = (blockIdx.x & 255) << 6;
    const float* pb = pts + (size_t)b * 64 * NPT;
    int tx = threadIdx.x & 63, ty = threadIdx.x >> 6;  // ty in 0..3
#pragma unroll
    for (int k = 0; k < 16; ++k) {
        int c = ty * 16 + k;
        t[c][tx] = pb[(size_t)c * NPT + n0 + tx];      // coalesced in n
    }
    __syncthreads();
#pragma unroll
    for (int k = 0; k < 16; ++k) {
        int n = ty * 16 + k;
        ptsT[((size_t)b * NPT + n0 + n) * 64 + tx] = t[tx][n];  // coalesced in c
    }
}

// ---------------- layer1: gather + GEMM(67->64) + BN partial sums --------------
__global__ __launch_bounds__(256)
__attribute__((amdgpu_waves_per_eu(1, 4)))
void k_gemm1(const float* __restrict__ xyz,
        const float* __restrict__ ptsT, const float* __restrict__ nxyz,
        const int* __restrict__ ballidx, const float* __restrict__ w,
        const float* __restrict__ bias, float* __restrict__ Y,
        float* __restrict__ sumP, float* __restrict__ sqP) {
    __shared__ float wlds[C1 * O1];   // [c][o]
    __shared__ float blds[O1];
    __shared__ float lsum[4][O1];
    __shared__ float lsq[4][O1];
    for (int i = threadIdx.x; i < C1 * O1; i += 256) {
        int c = i >> 6, o = i & 63;
        wlds[i] = w[o * C1 + c];
    }
    if (threadIdx.x < O1) blds[threadIdx.x] = bias[threadIdx.x];
    __syncthreads();
    int r = blockIdx.x * 256 + threadIdx.x;
    int b = r >> 15;
    int g = r >> 5;
    int id = ballidx[r];
    const float* xb = xyz + (size_t)b * 3 * NPT;
    float acc[O1];
#pragma unroll
    for (int o = 0; o < O1; ++o) acc[o] = blds[o];
#pragma unroll
    for (int c = 0; c < 3; ++c) {
        float xv = xb[c * NPT + id] - nxyz[g * 3 + c];
        const float* wr = &wlds[c * O1];
#pragma unroll
        for (int o = 0; o < O1; ++o) acc[o] = fmaf(xv, wr[o], acc[o]);
    }
    const float4* p4 = (const float4*)(ptsT + ((size_t)b * NPT + id) * 64);
#pragma unroll 4
    for (int cc = 0; cc < 16; ++cc) {
        float4 x = p4[cc];
        float xs[4] = {x.x, x.y, x.z, x.w};
#pragma unroll
        for (int u = 0; u < 4; ++u) {
            const float* wr = &wlds[(3 + cc * 4 + u) * O1];
#pragma unroll
            for (int o = 0; o < O1; ++o) acc[o] = fmaf(xs[u], wr[o], acc[o]);
        }
    }
    float4* yr = (float4*)(Y + (size_t)r * O1);
#pragma unroll
    for (int o4 = 0; o4 < O1 / 4; ++o4)
        yr[o4] = make_float4(acc[o4 * 4], acc[o4 * 4 + 1], acc[o4 * 4 + 2], acc[o4 * 4 + 3]);
    int lane = threadIdx.x & 63, wvv = threadIdx.x >> 6;
#pragma unroll
    for (int o = 0; o < O1; ++o) {
        float v = acc[o], v2 = acc[o] * acc[o];
#pragma unroll
        for (int off = 1; off < 64; off <<= 1) { v += __shfl_xor(v, off); v2 += __shfl_xor(v2, off); }
        if (lane == 0) { lsum[wvv][o] = v; lsq[wvv][o] = v2; }
    }
    __syncthreads();
    if (threadIdx.x < O1) {
        int o = threadIdx.x;
        sumP[blockIdx.x * O1 + o] = lsum[0][o] + lsum[1][o] + lsum[2][o] + lsum[3][o];
        sqP[blockIdx.x * O1 + o]  = lsq[0][o] + lsq[1][o] + lsq[2][o] + lsq[3][o];
    }
}

// ---------------- generic MLP layer: 64 outputs PER BLOCK ----------------------
// OTOT total outputs; blockIdx.y selects which 64-wide half this block computes.
// NORM_IN applies relu(x*isc+ish) to input rows. WRITE_Y stores raw y.
// PARTIALS: BN partial sums. MAXOUT: raw max over each 32-row group -> ymax
// (layout (B,O3,S)); valid because the later relu(y*sc+sh) is monotone (sc>0),
// so max commutes with it bitwise -- deletes the whole pass-B GEMM.
template <int CIN, int OTOT, bool NORM_IN, bool WRITE_Y, bool PARTIALS, bool MAXOUT>
__global__ __launch_bounds__(256)
__attribute__((amdgpu_waves_per_eu(1, 4)))
void k_mlp(
        const float* __restrict__ Yin, const float* __restrict__ w,
        const float* __restrict__ bias, const float* __restrict__ isc,
        const float* __restrict__ ish, float* __restrict__ Yout,
        float* __restrict__ sumP, float* __restrict__ sqP,
        float* __restrict__ ymax) {
    const int h = blockIdx.y;            // 64-wide output half (0 or OTOT/64-1)
    const int ob = h * 64;               // output base
    __shared__ float wlds[CIN * 64];     // [c][o] for this half
    __shared__ float blds[64];
    __shared__ float iscl[NORM_IN ? CIN : 1], ishl[NORM_IN ? CIN : 1];
    __shared__ float lsum[PARTIALS ? 4 : 1][PARTIALS ? 64 : 1];
    __shared__ float lsq[PARTIALS ? 4 : 1][PARTIALS ? 64 : 1];
    for (int i = threadIdx.x; i < CIN * 64; i += 256) {
        int c = i >> 6, o = i & 63;
        wlds[i] = w[(ob + o) * CIN + c];
    }
    if (threadIdx.x < 64) blds[threadIdx.x] = bias[ob + threadIdx.x];
    if (NORM_IN) {
        for (int i = threadIdx.x; i < CIN; i += 256) { iscl[i] = isc[i]; ishl[i] = ish[i]; }
    }
    __syncthreads();
    int r = blockIdx.x * 256 + threadIdx.x;
    float acc[64];
#pragma unroll
    for (int o = 0; o < 64; ++o) acc[o] = blds[o];
    const float4* r4 = (const float4*)(Yin + (size_t)r * CIN);
#pragma unroll 4
    for (int cc = 0; cc < CIN / 4; ++cc) {
        float4 x = r4[cc];
        float xs[4] = {x.x, x.y, x.z, x.w};
#pragma unroll
        for (int u = 0; u < 4; ++u) {
            int c = cc * 4 + u;
            float xv = xs[u];
            if (NORM_IN) xv = fmaxf(fmaf(xv, iscl[c], ishl[c]), 0.0f);
            const float* wr = &wlds[c * 64];
#pragma unroll
            for (int o = 0; o < 64; ++o) acc[o] = fmaf(xv, wr[o], acc[o]);
        }
    }
    if (WRITE_Y) {
        float4* yr = (float4*)(Yout + (size_t)r * OTOT + ob);
#pragma unroll
        for (int o4 = 0; o4 < 16; ++o4)
            yr[o4] = make_float4(acc[o4 * 4], acc[o4 * 4 + 1], acc[o4 * 4 + 2], acc[o4 * 4 + 3]);
    }
    if (PARTIALS) {
        int lane = threadIdx.x & 63, wvv = threadIdx.x >> 6;
#pragma unroll
        for (int o = 0; o < 64; ++o) {
            float v = acc[o], v2 = acc[o] * acc[o];
#pragma unroll
            for (int off = 1; off < 64; off <<= 1) { v += __shfl_xor(v, off); v2 += __shfl_xor(v2, off); }
            if (lane == 0) { lsum[wvv][o] = v; lsq[wvv][o] = v2; }
        }
        __syncthreads();
        if (threadIdx.x < 64) {
            int o = threadIdx.x;
            sumP[blockIdx.x * OTOT + ob + o] = lsum[0][o] + lsum[1][o] + lsum[2][o] + lsum[3][o];
            sqP[blockIdx.x * OTOT + ob + o]  = lsq[0][o] + lsq[1][o] + lsq[2][o] + lsq[3][o];
        }
    }
    if (MAXOUT) {
        int b = r >> 15, s = (r >> 5) & (SS - 1);
#pragma unroll
        for (int o = 0; o < 64; ++o) {
            float v = acc[o];
#pragma unroll
            for (int off = 1; off < 32; off <<= 1) v = fmaxf(v, __shfl_xor(v, off));
            if ((threadIdx.x & 31) == 0)
                ymax[((size_t)b * O3 + ob + o) * SS + s] = v;
        }
    }
}

// ---------------- pool epilogue: out1 = relu(ymax*sc + sh), coalesced ----------
__global__ __launch_bounds__(256) void k_pool(const float* __restrict__ ymax,
                                              const float* __restrict__ sc,
                                              const float* __restrict__ sh,
                                              float* __restrict__ out1) {
    int i = blockIdx.x * 256 + threadIdx.x;    // over BB*O3*SS, layout == out1
    int o = (i >> 10) & (O3 - 1);              // wave-uniform channel
    out1[i] = fmaxf(fmaf(ymax[i], sc[o], sh[o]), 0.0f);
}

// ---------------- finalize BN stats: 512 partials -> scale/shift ---------------
template <int COUT>
__global__ void k_finalize(const float* __restrict__ sumP, const float* __restrict__ sqP,
                           const float* __restrict__ g, const float* __restrict__ beta,
                           float* __restrict__ scale, float* __restrict__ shift) {
    __shared__ float ls[4][COUT], lq[4][COUT];
    int o = threadIdx.x % COUT, q = threadIdx.x / COUT;
    float s = 0.f, qq = 0.f;
    for (int bk = q; bk < 512; bk += 4) { s += sumP[bk * COUT + o]; qq += sqP[bk * COUT + o]; }
    ls[q][o] = s; lq[q][o] = qq;
    __syncthreads();
    if (q == 0) {
        s  = ls[0][o] + ls[1][o] + ls[2][o] + ls[3][o];
        qq = lq[0][o] + lq[1][o] + lq[2][o] + lq[3][o];
        const float inv = 1.0f / (float)RR;
        float mean = s * inv;
        float var = qq * inv - mean * mean;
        float sc = g[o] * rsqrtf(var + EPSF);
        scale[o] = sc;
        shift[o] = beta[o] - mean * sc;
    }
}

extern "C" void kernel_launch(void* const* d_in, const int* in_sizes, int n_in,
                              void* d_out, int out_size, void* d_ws, size_t ws_size,
                              hipStream_t stream) {
    const float* xyz = (const float*)d_in[0];
    const float* pts = (const float*)d_in[1];
    const float* w1  = (const float*)d_in[2];
    const float* b1  = (const float*)d_in[3];
    const float* g1  = (const float*)d_in[4];
    const float* bt1 = (const float*)d_in[5];
    const float* w2  = (const float*)d_in[6];
    const float* b2  = (const float*)d_in[7];
    const float* g2  = (const float*)d_in[8];
    const float* bt2 = (const float*)d_in[9];
    const float* w3  = (const float*)d_in[10];
    const float* b3  = (const float*)d_in[11];
    const float* g3  = (const float*)d_in[12];
    const float* bt3 = (const float*)d_in[13];
    float* out0 = (float*)d_out;                 // (B,3,S)
    float* out1 = out0 + BB * 3 * SS;            // (B,128,S)

    char* wsb = (char*)d_ws;
    size_t off = 0;
    auto alloc = [&](size_t bytes) {
        char* p = wsb + off;
        off += (bytes + 255) & ~(size_t)255;
        return p;
    };
    int*   fps_idx = (int*)alloc((size_t)BB * SS * 4);
    int*   ballidx = (int*)alloc((size_t)RR * 4);
    float* nxyz    = (float*)alloc((size_t)BB * SS * 3 * 4);
    float* sumP    = (float*)alloc((size_t)512 * 128 * 4);
    float* sqP     = (float*)alloc((size_t)512 * 128 * 4);
    float* sc1     = (float*)alloc(128 * 4);
    float* sh1     = (float*)alloc(128 * 4);
    float* sc2     = (float*)alloc(128 * 4);
    float* sh2     = (float*)alloc(128 * 4);
    float* sc3     = (float*)alloc(128 * 4);
    float* sh3     = (float*)alloc(128 * 4);
    float* ymax    = (float*)alloc((size_t)BB * O3 * SS * 4);
    float* Y1      = (float*)alloc((size_t)RR * 64 * 4);
    float* Y2      = (float*)alloc((size_t)RR * 64 * 4);
    float* ptsT    = Y2;   // ptsT (16 MB) lives in Y2's slot; Y2 written after gemm1

    k_tr<<<1024, 256, 0, stream>>>(pts, ptsT);
    k_fps<<<BB, FT, 0, stream>>>(xyz, fps_idx);
    k_newxyz<<<16, 256, 0, stream>>>(xyz, fps_idx, out0, nxyz);
    k_ball<<<1024, 256, 0, stream>>>(xyz, nxyz, ballidx);

    k_gemm1<<<512, 256, 0, stream>>>(xyz, ptsT, nxyz, ballidx, w1, b1, Y1, sumP, sqP);
    k_finalize<64><<<1, 256, 0, stream>>>(sumP, sqP, g1, bt1, sc1, sh1);

    k_mlp<64, 64, true, true, true, false><<<dim3(512, 1), 256, 0, stream>>>(
        Y1, w2, b2, sc1, sh1, Y2, sumP, sqP, nullptr);
    k_finalize<64><<<1, 256, 0, stream>>>(sumP, sqP, g2, bt2, sc2, sh2);

    k_mlp<64, 128, true, false, true, true><<<dim3(512, 2), 256, 0, stream>>>(
        Y2, w3, b3, sc2, sh2, nullptr, sumP, sqP, ymax);
    k_finalize<128><<<1, 512, 0, stream>>>(sumP, sqP, g3, bt3, sc3, sh3);

    k_pool<<<BB * O3 * SS / 256, 256, 0, stream>>>(ymax, sc3, sh3, out1);
}

// Round 12
// 1861.376 us; speedup vs baseline: 1.1038x; 1.1038x over previous
//
#include <hip/hip_runtime.h>
#include <hip/hip_bf16.h>
#include <stdint.h>

#define NPT   16384   // N
#define BB    4
#define SS    1024    // NPOINT
#define KK    32      // NSAMPLE
#define RR    (BB*SS*KK) // 131072 rows
#define C1    67
#define O1    64
#define O3    128
#define EPSF  1e-5f
#define R2F   0.09f   // f32(0.09)
#define FT    1024    // FPS threads/block
#define FE    16      // FPS elements/thread
#define BIGI  0x7fffffff

#define REP16(M) M(0) M(1) M(2) M(3) M(4) M(5) M(6) M(7) \
                 M(8) M(9) M(10) M(11) M(12) M(13) M(14) M(15)
#define REP16R(M) M(15) M(14) M(13) M(12) M(11) M(10) M(9) M(8) \
                  M(7) M(6) M(5) M(4) M(3) M(2) M(1) M(0)

// butterfly f32 max across a wave: 5 ds_swizzle levels + cross-32 shuffle
#define WMAX5(v) { \
    v = fmaxf(v, __int_as_float(__builtin_amdgcn_ds_swizzle(__float_as_int(v), 0x041F))); \
    v = fmaxf(v, __int_as_float(__builtin_amdgcn_ds_swizzle(__float_as_int(v), 0x081F))); \
    v = fmaxf(v, __int_as_float(__builtin_amdgcn_ds_swizzle(__float_as_int(v), 0x101F))); \
    v = fmaxf(v, __int_as_float(__builtin_amdgcn_ds_swizzle(__float_as_int(v), 0x201F))); \
    v = fmaxf(v, __int_as_float(__builtin_amdgcn_ds_swizzle(__float_as_int(v), 0x401F))); }

// ---------------- fused FPS (blocks 0..3) + pts transpose (blocks 4..1027) ----
// FPS path == R9's verified 1404us kernel (scalar exact-rn math; R10/R11
// packed-math variants were respectively broken and slower) with ONE delta:
// the serialized 16-deep same-address atomicMax value-reduce is replaced by
// R8's conflict-free s_red[16] write + 4-level swizzle merge (off the
// barrier-A critical path). Index+z still travel in one u64 atomicMin key.
// Transpose blocks (pts (B,64,N) -> ptsT (B,N,64)) run on the 252 idle CUs,
// hiding the old k_tr dispatch entirely; their tile aliases sxy's LDS.
__global__ __launch_bounds__(FT)
__attribute__((amdgpu_waves_per_eu(4, 4)))
void k_fps(const float* __restrict__ xyz, int* __restrict__ fps_idx,
           const float* __restrict__ pts, float* __restrict__ ptsT) {
    const int tid = threadIdx.x;
    const int lane = tid & 63, wv = tid >> 6;      // 16 waves

    __shared__ float2 sxy[NPT];                    // 128 KB: (x,y) interleaved
    __shared__ float s_red[16];                    // per-wave max partials
    __shared__ unsigned long long s_wz[2];         // double-buffered (idx,z) cell

    if (blockIdx.x >= BB) {
        // ---- transpose path: 64x64 tile per block, 16 waves x 4 rows ----
        int bid = blockIdx.x - BB;
        int b = bid >> 8, n0 = (bid & 255) << 6;
        float* t = (float*)sxy;                    // [64][65] alias (16.6 KB)
        const float* pb = pts + (size_t)b * 64 * NPT;
        int tx = tid & 63, ty = tid >> 6;          // ty in 0..15
#pragma unroll
        for (int k = 0; k < 4; ++k) {
            int c = ty * 4 + k;
            t[c * 65 + tx] = pb[(size_t)c * NPT + n0 + tx];   // coalesced in n
        }
        __syncthreads();
#pragma unroll
        for (int k = 0; k < 4; ++k) {
            int n = ty * 4 + k;
            ptsT[((size_t)b * NPT + n0 + n) * 64 + tx] = t[tx * 65 + n];
        }
        return;
    }

    // ---- FPS path ----
    const int b = blockIdx.x;
    const float* xb = xyz + (size_t)b * 3 * NPT;

#define DECLV(i) float Z##i, D##i;
    REP16(DECLV)
#define INITV(i) { int n = (i) * FT + tid; \
                   float xx = xb[n]; \
                   float yy = xb[NPT + n]; \
                   float zz = xb[2 * NPT + n]; \
                   sxy[n] = make_float2(xx, yy); \
                   asm volatile("" : "+v"(zz)); \
                   Z##i = zz; D##i = 1e10f; }
    REP16(INITV)
    if (tid == 0) { s_wz[0] = ~0ull; s_wz[1] = ~0ull; }
    __syncthreads();                               // sxy + cells visible

    int p = 0;
    int far = 0;
    float2 c0 = sxy[0];
    float cx = c0.x, cy = c0.y, cz = xb[2 * NPT];
    for (int it = 0; it < SS; ++it) {
        if (tid == 0) fps_idx[b * SS + it] = far;
        // exact reference arithmetic: (dx*dx + dy*dy) + dz*dz, no FMA
#define UPDV(i) { float2 xy = sxy[(i) * FT + tid]; \
                  float dx = __fsub_rn(xy.x, cx); \
                  float dy = __fsub_rn(xy.y, cy); \
                  float dz = __fsub_rn(Z##i, cz); \
                  float d = __fadd_rn(__fadd_rn(__fmul_rn(dx, dx), __fmul_rn(dy, dy)), \
                                      __fmul_rn(dz, dz)); \
                  D##i = fminf(D##i, d); }
        REP16(UPDV)
        // depth-4 tree max of the 16 updated dists
        float m0 = fmaxf(fmaxf(D0, D1), fmaxf(D2, D3));
        float m1 = fmaxf(fmaxf(D4, D5), fmaxf(D6, D7));
        float m2 = fmaxf(fmaxf(D8, D9), fmaxf(D10, D11));
        float m3 = fmaxf(fmaxf(D12, D13), fmaxf(D14, D15));
        float tbd = fmaxf(fmaxf(m0, m1), fmaxf(m2, m3));   // thread max

        float bd = tbd;
        WMAX5(bd)
        bd = fmaxf(bd, __shfl_xor(bd, 32));                // wave max
        if (lane == 0) s_red[wv] = bd;                     // own cell, no atomic
        __syncthreads();                  // barrier A: partials ready
        if (tid == 0) s_wz[p ^ 1] = ~0ull;                 // prep next iter
        // merge 16 partials: every 16-lane group holds all 16 -> 4 xor levels
        float Mf = s_red[lane & 15];
        Mf = fmaxf(Mf, __int_as_float(__builtin_amdgcn_ds_swizzle(__float_as_int(Mf), 0x041F)));
        Mf = fmaxf(Mf, __int_as_float(__builtin_amdgcn_ds_swizzle(__float_as_int(Mf), 0x081F)));
        Mf = fmaxf(Mf, __int_as_float(__builtin_amdgcn_ds_swizzle(__float_as_int(Mf), 0x101F)));
        Mf = fmaxf(Mf, __int_as_float(__builtin_amdgcn_ds_swizzle(__float_as_int(Mf), 0x201F)));
        if (tbd == Mf) {                  // only threads holding the max scan
            int bn = BIGI; float zw = 0.0f;
            // descending i so the LOWEST matching index is assigned last
#define SCANV(i) { bool m = (D##i == Mf); \
                   bn = m ? ((i) * FT + tid) : bn; \
                   zw = m ? Z##i : zw; }
            REP16R(SCANV)
            atomicMin(&s_wz[p], ((unsigned long long)(unsigned)bn << 32) |
                                (unsigned long long)__float_as_uint(zw));
        }
        __syncthreads();                  // barrier B: winner ready
        unsigned long long wz = s_wz[p];
        far = (int)(wz >> 32);
        cz = __uint_as_float((unsigned)wz);
        float2 cxy = sxy[far];            // uniform addr -> LDS broadcast
        cx = cxy.x; cy = cxy.y;
        p ^= 1;
    }
#undef DECLV
#undef INITV
#undef UPDV
#undef SCANV
}

// ---------------- gather new_xyz: output0 (B,3,S) + ws copy (b,s,3) ------------
__global__ void k_newxyz(const float* __restrict__ xyz, const int* __restrict__ fps_idx,
                         float* __restrict__ out0, float* __restrict__ nxyz) {
    int g = blockIdx.x * blockDim.x + threadIdx.x;
    if (g >= BB * SS) return;
    int b = g / SS, s = g % SS;
    int id = fps_idx[g];
    const float* xb = xyz + (size_t)b * 3 * NPT;
#pragma unroll
    for (int c = 0; c < 3; ++c) {
        float v = xb[c * NPT + id];
        out0[(size_t)b * 3 * SS + c * SS + s] = v;
        nxyz[g * 3 + c] = v;
    }
}

// ---------------- ball query: one wave per centroid, ballot ranking ------------
__global__ __launch_bounds__(256) void k_ball(const float* __restrict__ xyz,
                                              const float* __restrict__ nxyz,
                                              int* __restrict__ ballidx) {
    int wid = (blockIdx.x * 256 + threadIdx.x) >> 6;   // 0..4095
    int lane = threadIdx.x & 63;
    int b = wid >> 10;
    const float* xb = xyz + (size_t)b * 3 * NPT;
    float nx = nxyz[wid * 3], ny = nxyz[wid * 3 + 1], nz = nxyz[wid * 3 + 2];
    int* out = ballidx + (size_t)wid * KK;
    int cnt = 0;
    int first = -1;
    for (int base = 0; base < NPT; base += 64) {
        int n = base + lane;
        float dx = __fsub_rn(nx, xb[n]);
        float dy = __fsub_rn(ny, xb[NPT + n]);
        float dz = __fsub_rn(nz, xb[2 * NPT + n]);
        float d = __fadd_rn(__fadd_rn(__fmul_rn(dx, dx), __fmul_rn(dy, dy)),
                            __fmul_rn(dz, dz));
        bool hit = !(d > R2F);            // excluded iff sqr > r^2 (matches ref)
        unsigned long long mask = __ballot(hit);
        if (mask) {
            if (first < 0) first = base + __builtin_ctzll(mask);
            int rank = cnt + __popcll(mask & ((1ull << lane) - 1ull));
            if (hit && rank < KK) out[rank] = n;
            cnt += __popcll(mask);
        }
        if (cnt >= KK) break;
    }
    if (lane >= cnt && lane < KK) out[lane] = first;   // pad with first hit
}

// ---------------- layer1: gather + GEMM(67->64) + BN partial sums --------------
__global__ __launch_bounds__(256)
__attribute__((amdgpu_waves_per_eu(1, 4)))
void k_gemm1(const float* __restrict__ xyz,
        const float* __restrict__ ptsT, const float* __restrict__ nxyz,
        const int* __restrict__ ballidx, const float* __restrict__ w,
        const float* __restrict__ bias, float* __restrict__ Y,
        float* __restrict__ sumP, float* __restrict__ sqP) {
    __shared__ float wlds[C1 * O1];   // [c][o]
    __shared__ float blds[O1];
    __shared__ float lsum[4][O1];
    __shared__ float lsq[4][O1];
    for (int i = threadIdx.x; i < C1 * O1; i += 256) {
        int c = i >> 6, o = i & 63;
        wlds[i] = w[o * C1 + c];
    }
    if (threadIdx.x < O1) blds[threadIdx.x] = bias[threadIdx.x];
    __syncthreads();
    int r = blockIdx.x * 256 + threadIdx.x;
    int b = r >> 15;
    int g = r >> 5;
    int id = ballidx[r];
    const float* xb = xyz + (size_t)b * 3 * NPT;
    float acc[O1];
#pragma unroll
    for (int o = 0; o < O1; ++o) acc[o] = blds[o];
#pragma unroll
    for (int c = 0; c < 3; ++c) {
        float xv = xb[c * NPT + id] - nxyz[g * 3 + c];
        const float* wr = &wlds[c * O1];
#pragma unroll
        for (int o = 0; o < O1; ++o) acc[o] = fmaf(xv, wr[o], acc[o]);
    }
    const float4* p4 = (const float4*)(ptsT + ((size_t)b * NPT + id) * 64);
#pragma unroll 4
    for (int cc = 0; cc < 16; ++cc) {
        float4 x = p4[cc];
        float xs[4] = {x.x, x.y, x.z, x.w};
#pragma unroll
        for (int u = 0; u < 4; ++u) {
            const float* wr = &wlds[(3 + cc * 4 + u) * O1];
#pragma unroll
            for (int o = 0; o < O1; ++o) acc[o] = fmaf(xs[u], wr[o], acc[o]);
        }
    }
    float4* yr = (float4*)(Y + (size_t)r * O1);
#pragma unroll
    for (int o4 = 0; o4 < O1 / 4; ++o4)
        yr[o4] = make_float4(acc[o4 * 4], acc[o4 * 4 + 1], acc[o4 * 4 + 2], acc[o4 * 4 + 3]);
    int lane = threadIdx.x & 63, wvv = threadIdx.x >> 6;
#pragma unroll
    for (int o = 0; o < O1; ++o) {
        float v = acc[o], v2 = acc[o] * acc[o];
#pragma unroll
        for (int off = 1; off < 64; off <<= 1) { v += __shfl_xor(v, off); v2 += __shfl_xor(v2, off); }
        if (lane == 0) { lsum[wvv][o] = v; lsq[wvv][o] = v2; }
    }
    __syncthreads();
    if (threadIdx.x < O1) {
        int o = threadIdx.x;
        sumP[blockIdx.x * O1 + o] = lsum[0][o] + lsum[1][o] + lsum[2][o] + lsum[3][o];
        sqP[blockIdx.x * O1 + o]  = lsq[0][o] + lsq[1][o] + lsq[2][o] + lsq[3][o];
    }
}

// ---------------- generic MLP layer: 64 outputs PER BLOCK ----------------------
// OTOT total outputs; blockIdx.y selects which 64-wide half this block computes.
// NORM_IN applies relu(x*isc+ish) to input rows. WRITE_Y stores raw y.
// PARTIALS: BN partial sums. MAXOUT: raw max over each 32-row group -> ymax
// (layout (B,O3,S)); valid because the later relu(y*sc+sh) is monotone (sc>0),
// so max commutes with it bitwise -- deletes the whole pass-B GEMM.
template <int CIN, int OTOT, bool NORM_IN, bool WRITE_Y, bool PARTIALS, bool MAXOUT>
__global__ __launch_bounds__(256)
__attribute__((amdgpu_waves_per_eu(1, 4)))
void k_mlp(
        const float* __restrict__ Yin, const float* __restrict__ w,
        const float* __restrict__ bias, const float* __restrict__ isc,
        const float* __restrict__ ish, float* __restrict__ Yout,
        float* __restrict__ sumP, float* __restrict__ sqP,
        float* __restrict__ ymax) {
    const int h = blockIdx.y;            // 64-wide output half (0 or OTOT/64-1)
    const int ob = h * 64;               // output base
    __shared__ float wlds[CIN * 64];     // [c][o] for this half
    __shared__ float blds[64];
    __shared__ float iscl[NORM_IN ? CIN : 1], ishl[NORM_IN ? CIN : 1];
    __shared__ float lsum[PARTIALS ? 4 : 1][PARTIALS ? 64 : 1];
    __shared__ float lsq[PARTIALS ? 4 : 1][PARTIALS ? 64 : 1];
    for (int i = threadIdx.x; i < CIN * 64; i += 256) {
        int c = i >> 6, o = i & 63;
        wlds[i] = w[(ob + o) * CIN + c];
    }
    if (threadIdx.x < 64) blds[threadIdx.x] = bias[ob + threadIdx.x];
    if (NORM_IN) {
        for (int i = threadIdx.x; i < CIN; i += 256) { iscl[i] = isc[i]; ishl[i] = ish[i]; }
    }
    __syncthreads();
    int r = blockIdx.x * 256 + threadIdx.x;
    float acc[64];
#pragma unroll
    for (int o = 0; o < 64; ++o) acc[o] = blds[o];
    const float4* r4 = (const float4*)(Yin + (size_t)r * CIN);
#pragma unroll 4
    for (int cc = 0; cc < CIN / 4; ++cc) {
        float4 x = r4[cc];
        float xs[4] = {x.x, x.y, x.z, x.w};
#pragma unroll
        for (int u = 0; u < 4; ++u) {
            int c = cc * 4 + u;
            float xv = xs[u];
            if (NORM_IN) xv = fmaxf(fmaf(xv, iscl[c], ishl[c]), 0.0f);
            const float* wr = &wlds[c * 64];
#pragma unroll
            for (int o = 0; o < 64; ++o) acc[o] = fmaf(xv, wr[o], acc[o]);
        }
    }
    if (WRITE_Y) {
        float4* yr = (float4*)(Yout + (size_t)r * OTOT + ob);
#pragma unroll
        for (int o4 = 0; o4 < 16; ++o4)
            yr[o4] = make_float4(acc[o4 * 4], acc[o4 * 4 + 1], acc[o4 * 4 + 2], acc[o4 * 4 + 3]);
    }
    if (PARTIALS) {
        int lane = threadIdx.x & 63, wvv = threadIdx.x >> 6;
#pragma unroll
        for (int o = 0; o < 64; ++o) {
            float v = acc[o], v2 = acc[o] * acc[o];
#pragma unroll
            for (int off = 1; off < 64; off <<= 1) { v += __shfl_xor(v, off); v2 += __shfl_xor(v2, off); }
            if (lane == 0) { lsum[wvv][o] = v; lsq[wvv][o] = v2; }
        }
        __syncthreads();
        if (threadIdx.x < 64) {
            int o = threadIdx.x;
            sumP[blockIdx.x * OTOT + ob + o] = lsum[0][o] + lsum[1][o] + lsum[2][o] + lsum[3][o];
            sqP[blockIdx.x * OTOT + ob + o]  = lsq[0][o] + lsq[1][o] + lsq[2][o] + lsq[3][o];
        }
    }
    if (MAXOUT) {
        int b = r >> 15, s = (r >> 5) & (SS - 1);
#pragma unroll
        for (int o = 0; o < 64; ++o) {
            float v = acc[o];
#pragma unroll
            for (int off = 1; off < 32; off <<= 1) v = fmaxf(v, __shfl_xor(v, off));
            if ((threadIdx.x & 31) == 0)
                ymax[((size_t)b * O3 + ob + o) * SS + s] = v;
        }
    }
}

// ---------------- pool epilogue: out1 = relu(ymax*sc + sh), coalesced ----------
__global__ __launch_bounds__(256) void k_pool(const float* __restrict__ ymax,
                                              const float* __restrict__ sc,
                                              const float* __restrict__ sh,
                                              float* __restrict__ out1) {
    int i = blockIdx.x * 256 + threadIdx.x;    // over BB*O3*SS, layout == out1
    int o = (i >> 10) & (O3 - 1);              // wave-uniform channel
    out1[i] = fmaxf(fmaf(ymax[i], sc[o], sh[o]), 0.0f);
}

// ---------------- finalize BN stats: 512 partials -> scale/shift ---------------
template <int COUT>
__global__ void k_finalize(const float* __restrict__ sumP, const float* __restrict__ sqP,
                           const float* __restrict__ g, const float* __restrict__ beta,
                           float* __restrict__ scale, float* __restrict__ shift) {
    __shared__ float ls[4][COUT], lq[4][COUT];
    int o = threadIdx.x % COUT, q = threadIdx.x / COUT;
    float s = 0.f, qq = 0.f;
    for (int bk = q; bk < 512; bk += 4) { s += sumP[bk * COUT + o]; qq += sqP[bk * COUT + o]; }
    ls[q][o] = s; lq[q][o] = qq;
    __syncthreads();
    if (q == 0) {
        s  = ls[0][o] + ls[1][o] + ls[2][o] + ls[3][o];
        qq = lq[0][o] + lq[1][o] + lq[2][o] + lq[3][o];
        const float inv = 1.0f / (float)RR;
        float mean = s * inv;
        float var = qq * inv - mean * mean;
        float sc = g[o] * rsqrtf(var + EPSF);
        scale[o] = sc;
        shift[o] = beta[o] - mean * sc;
    }
}

extern "C" void kernel_launch(void* const* d_in, const int* in_sizes, int n_in,
                              void* d_out, int out_size, void* d_ws, size_t ws_size,
                              hipStream_t stream) {
    const float* xyz = (const float*)d_in[0];
    const float* pts = (const float*)d_in[1];
    const float* w1  = (const float*)d_in[2];
    const float* b1  = (const float*)d_in[3];
    const float* g1  = (const float*)d_in[4];
    const float* bt1 = (const float*)d_in[5];
    const float* w2  = (const float*)d_in[6];
    const float* b2  = (const float*)d_in[7];
    const float* g2  = (const float*)d_in[8];
    const float* bt2 = (const float*)d_in[9];
    const float* w3  = (const float*)d_in[10];
    const float* b3  = (const float*)d_in[11];
    const float* g3  = (const float*)d_in[12];
    const float* bt3 = (const float*)d_in[13];
    float* out0 = (float*)d_out;                 // (B,3,S)
    float* out1 = out0 + BB * 3 * SS;            // (B,128,S)

    char* wsb = (char*)d_ws;
    size_t off = 0;
    auto alloc = [&](size_t bytes) {
        char* p = wsb + off;
        off += (bytes + 255) & ~(size_t)255;
        return p;
    };
    int*   fps_idx = (int*)alloc((size_t)BB * SS * 4);
    int*   ballidx = (int*)alloc((size_t)RR * 4);
    float* nxyz    = (float*)alloc((size_t)BB * SS * 3 * 4);
    float* sumP    = (float*)alloc((size_t)512 * 128 * 4);
    float* sqP     = (float*)alloc((size_t)512 * 128 * 4);
    float* sc1     = (float*)alloc(128 * 4);
    float* sh1     = (float*)alloc(128 * 4);
    float* sc2     = (float*)alloc(128 * 4);
    float* sh2     = (float*)alloc(128 * 4);
    float* sc3     = (float*)alloc(128 * 4);
    float* sh3     = (float*)alloc(128 * 4);
    float* ymax    = (float*)alloc((size_t)BB * O3 * SS * 4);
    float* Y1      = (float*)alloc((size_t)RR * 64 * 4);
    float* Y2      = (float*)alloc((size_t)RR * 64 * 4);
    float* ptsT    = Y2;   // ptsT (16 MB) lives in Y2's slot; Y2 written after gemm1

    // fused: blocks 0..3 run FPS (4 CUs); blocks 4..1027 transpose pts on the
    // other 252 CUs, fully hidden under the 1.4 ms FPS tail.
    k_fps<<<BB + 1024, FT, 0, stream>>>(xyz, fps_idx, pts, ptsT);
    k_newxyz<<<16, 256, 0, stream>>>(xyz, fps_idx, out0, nxyz);
    k_ball<<<1024, 256, 0, stream>>>(xyz, nxyz, ballidx);

    k_gemm1<<<512, 256, 0, stream>>>(xyz, ptsT, nxyz, ballidx, w1, b1, Y1, sumP, sqP);
    k_finalize<64><<<1, 256, 0, stream>>>(sumP, sqP, g1, bt1, sc1, sh1);

    k_mlp<64, 64, true, true, true, false><<<dim3(512, 1), 256, 0, stream>>>(
        Y1, w2, b2, sc1, sh1, Y2, sumP, sqP, nullptr);
    k_finalize<64><<<1, 256, 0, stream>>>(sumP, sqP, g2, bt2, sc2, sh2);

    k_mlp<64, 128, true, false, true, true><<<dim3(512, 2), 256, 0, stream>>>(
        Y2, w3, b3, sc2, sh2, nullptr, sumP, sqP, ymax);
    k_finalize<128><<<1, 512, 0, stream>>>(sumP, sqP, g3, bt3, sc3, sh3);

    k_pool<<<BB * O3 * SS / 256, 256, 0, stream>>>(ymax, sc3, sh3, out1);
}

// Round 14
// 1730.695 us; speedup vs baseline: 1.1871x; 1.0755x over previous
//
#include <hip/hip_runtime.h>
#include <hip/hip_bf16.h>
#include <stdint.h>

#define NPT   16384   // N
#define BB    4
#define SS    1024    // NPOINT
#define KK    32      // NSAMPLE
#define RR    (BB*SS*KK) // 131072 rows
#define C1    67
#define O1    64
#define O3    128
#define EPSF  1e-5f
#define R2F   0.09f   // f32(0.09)
#define FT    1024    // FPS threads/block
#define FE    16      // FPS elements/thread
#define BIGI  0x7fffffff

#define REP16(M) M(0) M(1) M(2) M(3) M(4) M(5) M(6) M(7) \
                 M(8) M(9) M(10) M(11) M(12) M(13) M(14) M(15)
#define REP16R(M) M(15) M(14) M(13) M(12) M(11) M(10) M(9) M(8) \
                  M(7) M(6) M(5) M(4) M(3) M(2) M(1) M(0)

// DPP fmax step: VALU-resident lane exchange (~4-8 cyc vs ~40 for ds_swizzle).
// CTRL must be a compile-time constant -> template parameter (R13 compile fix).
template <int CTRL>
__device__ __forceinline__ float dpp_fmax(float v) {
    int iv = __float_as_int(v);
    int sh = __builtin_amdgcn_update_dpp(iv, iv, CTRL, 0xF, 0xF, true);
    return fmaxf(v, __int_as_float(sh));
}

// ---------------- fused FPS (blocks 0..3) + pts transpose (blocks 4..1027) ----
// R12 post-mortem: moving the value-merge AFTER barrier A (lockstep) cost 60us
// vs R9's PRE-barrier 16-deep atomicMax (hides in wave-arrival skew). This
// round: exact R9 reduce protocol restored (pre-barrier single-cell atomicMax,
// post-barrier broadcast read; idx+z in one u64 atomicMin key), fused
// transpose kept, and the wave-max butterfly's first 4 ds_swizzle levels
// replaced by DPP fmax (quad_perm xor1/xor2, row_half_mirror, row_mirror --
// full 16-lane combining network), then swizzle xor16 + shfl32 cross-row.
// Saves ~130 serial cyc/iter and relieves the DS pipe.
__global__ __launch_bounds__(FT)
__attribute__((amdgpu_waves_per_eu(4, 4)))
void k_fps(const float* __restrict__ xyz, int* __restrict__ fps_idx,
           const float* __restrict__ pts, float* __restrict__ ptsT) {
    const int tid = threadIdx.x;
    const int lane = tid & 63;

    __shared__ float2 sxy[NPT];                    // 128 KB: (x,y) interleaved
    __shared__ int s_M[2];                         // double-buffered max cell
    __shared__ unsigned long long s_wz[2];         // double-buffered (idx,z) cell

    if (blockIdx.x >= BB) {
        // ---- transpose path: 64x64 tile per block, 16 waves x 4 rows ----
        int bid = blockIdx.x - BB;
        int b = bid >> 8, n0 = (bid & 255) << 6;
        float* t = (float*)sxy;                    // [64][65] alias (16.6 KB)
        const float* pb = pts + (size_t)b * 64 * NPT;
        int tx = tid & 63, ty = tid >> 6;          // ty in 0..15
#pragma unroll
        for (int k = 0; k < 4; ++k) {
            int c = ty * 4 + k;
            t[c * 65 + tx] = pb[(size_t)c * NPT + n0 + tx];   // coalesced in n
        }
        __syncthreads();
#pragma unroll
        for (int k = 0; k < 4; ++k) {
            int n = ty * 4 + k;
            ptsT[((size_t)b * NPT + n0 + n) * 64 + tx] = t[tx * 65 + n];
        }
        return;
    }

    // ---- FPS path ----
    const int b = blockIdx.x;
    const float* xb = xyz + (size_t)b * 3 * NPT;

#define DECLV(i) float Z##i, D##i;
    REP16(DECLV)
#define INITV(i) { int n = (i) * FT + tid; \
                   float xx = xb[n]; \
                   float yy = xb[NPT + n]; \
                   float zz = xb[2 * NPT + n]; \
                   sxy[n] = make_float2(xx, yy); \
                   asm volatile("" : "+v"(zz)); \
                   Z##i = zz; D##i = 1e10f; }
    REP16(INITV)
    if (tid == 0) { s_M[0] = 0; s_M[1] = 0; s_wz[0] = ~0ull; s_wz[1] = ~0ull; }
    __syncthreads();                               // sxy + cells visible

    int p = 0;
    int far = 0;
    float2 c0 = sxy[0];
    float cx = c0.x, cy = c0.y, cz = xb[2 * NPT];
    for (int it = 0; it < SS; ++it) {
        if (tid == 0) fps_idx[b * SS + it] = far;
        // exact reference arithmetic: (dx*dx + dy*dy) + dz*dz, no FMA
#define UPDV(i) { float2 xy = sxy[(i) * FT + tid]; \
                  float dx = __fsub_rn(xy.x, cx); \
                  float dy = __fsub_rn(xy.y, cy); \
                  float dz = __fsub_rn(Z##i, cz); \
                  float d = __fadd_rn(__fadd_rn(__fmul_rn(dx, dx), __fmul_rn(dy, dy)), \
                                      __fmul_rn(dz, dz)); \
                  D##i = fminf(D##i, d); }
        REP16(UPDV)
        // depth-4 tree max of the 16 updated dists
        float m0 = fmaxf(fmaxf(D0, D1), fmaxf(D2, D3));
        float m1 = fmaxf(fmaxf(D4, D5), fmaxf(D6, D7));
        float m2 = fmaxf(fmaxf(D8, D9), fmaxf(D10, D11));
        float m3 = fmaxf(fmaxf(D12, D13), fmaxf(D14, D15));
        float tbd = fmaxf(fmaxf(m0, m1), fmaxf(m2, m3));   // thread max

        // wave max: 4 DPP levels (16-lane network) + swizzle xor16 + shfl 32
        float bd = tbd;
        bd = dpp_fmax<0xB1>(bd);   // quad_perm [1,0,3,2]: xor1
        bd = dpp_fmax<0x4E>(bd);   // quad_perm [2,3,0,1]: xor2
        bd = dpp_fmax<0x141>(bd);  // row_half_mirror: pairs quads within 8
        bd = dpp_fmax<0x140>(bd);  // row_mirror: pairs 8s within 16
        bd = fmaxf(bd, __int_as_float(__builtin_amdgcn_ds_swizzle(__float_as_int(bd), 0x401F)));
        bd = fmaxf(bd, __shfl_xor(bd, 32));                // wave max
        if (lane == 0) atomicMax(&s_M[p], __float_as_int(bd));  // pre-barrier: hides in skew
        __syncthreads();                  // barrier A: global max ready
        if (tid == 0) { s_M[p ^ 1] = 0; s_wz[p ^ 1] = ~0ull; }  // prep next iter
        float Mf = __int_as_float(s_M[p]);
        if (tbd == Mf) {                  // only threads holding the max scan
            int bn = BIGI; float zw = 0.0f;
            // descending i so the LOWEST matching index is assigned last
#define SCANV(i) { bool m = (D##i == Mf); \
                   bn = m ? ((i) * FT + tid) : bn; \
                   zw = m ? Z##i : zw; }
            REP16R(SCANV)
            atomicMin(&s_wz[p], ((unsigned long long)(unsigned)bn << 32) |
                                (unsigned long long)__float_as_uint(zw));
        }
        __syncthreads();                  // barrier B: winner ready
        unsigned long long wz = s_wz[p];
        far = (int)(wz >> 32);
        cz = __uint_as_float((unsigned)wz);
        float2 cxy = sxy[far];            // uniform addr -> LDS broadcast
        cx = cxy.x; cy = cxy.y;
        p ^= 1;
    }
#undef DECLV
#undef INITV
#undef UPDV
#undef SCANV
}

// ---------------- gather new_xyz: output0 (B,3,S) + ws copy (b,s,3) ------------
__global__ void k_newxyz(const float* __restrict__ xyz, const int* __restrict__ fps_idx,
                         float* __restrict__ out0, float* __restrict__ nxyz) {
    int g = blockIdx.x * blockDim.x + threadIdx.x;
    if (g >= BB * SS) return;
    int b = g / SS, s = g % SS;
    int id = fps_idx[g];
    const float* xb = xyz + (size_t)b * 3 * NPT;
#pragma unroll
    for (int c = 0; c < 3; ++c) {
        float v = xb[c * NPT + id];
        out0[(size_t)b * 3 * SS + c * SS + s] = v;
        nxyz[g * 3 + c] = v;
    }
}

// ---------------- ball query: one wave per centroid, ballot ranking ------------
__global__ __launch_bounds__(256) void k_ball(const float* __restrict__ xyz,
                                              const float* __restrict__ nxyz,
                                              int* __restrict__ ballidx) {
    int wid = (blockIdx.x * 256 + threadIdx.x) >> 6;   // 0..4095
    int lane = threadIdx.x & 63;
    int b = wid >> 10;
    const float* xb = xyz + (size_t)b * 3 * NPT;
    float nx = nxyz[wid * 3], ny = nxyz[wid * 3 + 1], nz = nxyz[wid * 3 + 2];
    int* out = ballidx + (size_t)wid * KK;
    int cnt = 0;
    int first = -1;
    for (int base = 0; base < NPT; base += 64) {
        int n = base + lane;
        float dx = __fsub_rn(nx, xb[n]);
        float dy = __fsub_rn(ny, xb[NPT + n]);
        float dz = __fsub_rn(nz, xb[2 * NPT + n]);
        float d = __fadd_rn(__fadd_rn(__fmul_rn(dx, dx), __fmul_rn(dy, dy)),
                            __fmul_rn(dz, dz));
        bool hit = !(d > R2F);            // excluded iff sqr > r^2 (matches ref)
        unsigned long long mask = __ballot(hit);
        if (mask) {
            if (first < 0) first = base + __builtin_ctzll(mask);
            int rank = cnt + __popcll(mask & ((1ull << lane) - 1ull));
            if (hit && rank < KK) out[rank] = n;
            cnt += __popcll(mask);
        }
        if (cnt >= KK) break;
    }
    if (lane >= cnt && lane < KK) out[lane] = first;   // pad with first hit
}

// ---------------- layer1: gather + GEMM(67->64) + BN partial sums --------------
__global__ __launch_bounds__(256)
__attribute__((amdgpu_waves_per_eu(1, 4)))
void k_gemm1(const float* __restrict__ xyz,
        const float* __restrict__ ptsT, const float* __restrict__ nxyz,
        const int* __restrict__ ballidx, const float* __restrict__ w,
        const float* __restrict__ bias, float* __restrict__ Y,
        float* __restrict__ sumP, float* __restrict__ sqP) {
    __shared__ float wlds[C1 * O1];   // [c][o]
    __shared__ float blds[O1];
    __shared__ float lsum[4][O1];
    __shared__ float lsq[4][O1];
    for (int i = threadIdx.x; i < C1 * O1; i += 256) {
        int c = i >> 6, o = i & 63;
        wlds[i] = w[o * C1 + c];
    }
    if (threadIdx.x < O1) blds[threadIdx.x] = bias[threadIdx.x];
    __syncthreads();
    int r = blockIdx.x * 256 + threadIdx.x;
    int b = r >> 15;
    int g = r >> 5;
    int id = ballidx[r];
    const float* xb = xyz + (size_t)b * 3 * NPT;
    float acc[O1];
#pragma unroll
    for (int o = 0; o < O1; ++o) acc[o] = blds[o];
#pragma unroll
    for (int c = 0; c < 3; ++c) {
        float xv = xb[c * NPT + id] - nxyz[g * 3 + c];
        const float* wr = &wlds[c * O1];
#pragma unroll
        for (int o = 0; o < O1; ++o) acc[o] = fmaf(xv, wr[o], acc[o]);
    }
    const float4* p4 = (const float4*)(ptsT + ((size_t)b * NPT + id) * 64);
#pragma unroll 4
    for (int cc = 0; cc < 16; ++cc) {
        float4 x = p4[cc];
        float xs[4] = {x.x, x.y, x.z, x.w};
#pragma unroll
        for (int u = 0; u < 4; ++u) {
            const float* wr = &wlds[(3 + cc * 4 + u) * O1];
#pragma unroll
            for (int o = 0; o < O1; ++o) acc[o] = fmaf(xs[u], wr[o], acc[o]);
        }
    }
    float4* yr = (float4*)(Y + (size_t)r * O1);
#pragma unroll
    for (int o4 = 0; o4 < O1 / 4; ++o4)
        yr[o4] = make_float4(acc[o4 * 4], acc[o4 * 4 + 1], acc[o4 * 4 + 2], acc[o4 * 4 + 3]);
    int lane = threadIdx.x & 63, wvv = threadIdx.x >> 6;
#pragma unroll
    for (int o = 0; o < O1; ++o) {
        float v = acc[o], v2 = acc[o] * acc[o];
#pragma unroll
        for (int off = 1; off < 64; off <<= 1) { v += __shfl_xor(v, off); v2 += __shfl_xor(v2, off); }
        if (lane == 0) { lsum[wvv][o] = v; lsq[wvv][o] = v2; }
    }
    __syncthreads();
    if (threadIdx.x < O1) {
        int o = threadIdx.x;
        sumP[blockIdx.x * O1 + o] = lsum[0][o] + lsum[1][o] + lsum[2][o] + lsum[3][o];
        sqP[blockIdx.x * O1 + o]  = lsq[0][o] + lsq[1][o] + lsq[2][o] + lsq[3][o];
    }
}

// ---------------- generic MLP layer: 64 outputs PER BLOCK ----------------------
// OTOT total outputs; blockIdx.y selects which 64-wide half this block computes.
// NORM_IN applies relu(x*isc+ish) to input rows. WRITE_Y stores raw y.
// PARTIALS: BN partial sums. MAXOUT: raw max over each 32-row group -> ymax
// (layout (B,O3,S)); valid because the later relu(y*sc+sh) is monotone (sc>0),
// so max commutes with it bitwise -- deletes the whole pass-B GEMM.
template <int CIN, int OTOT, bool NORM_IN, bool WRITE_Y, bool PARTIALS, bool MAXOUT>
__global__ __launch_bounds__(256)
__attribute__((amdgpu_waves_per_eu(1, 4)))
void k_mlp(
        const float* __restrict__ Yin, const float* __restrict__ w,
        const float* __restrict__ bias, const float* __restrict__ isc,
        const float* __restrict__ ish, float* __restrict__ Yout,
        float* __restrict__ sumP, float* __restrict__ sqP,
        float* __restrict__ ymax) {
    const int h = blockIdx.y;            // 64-wide output half (0 or OTOT/64-1)
    const int ob = h * 64;               // output base
    __shared__ float wlds[CIN * 64];     // [c][o] for this half
    __shared__ float blds[64];
    __shared__ float iscl[NORM_IN ? CIN : 1], ishl[NORM_IN ? CIN : 1];
    __shared__ float lsum[PARTIALS ? 4 : 1][PARTIALS ? 64 : 1];
    __shared__ float lsq[PARTIALS ? 4 : 1][PARTIALS ? 64 : 1];
    for (int i = threadIdx.x; i < CIN * 64; i += 256) {
        int c = i >> 6, o = i & 63;
        wlds[i] = w[(ob + o) * CIN + c];
    }
    if (threadIdx.x < 64) blds[threadIdx.x] = bias[ob + threadIdx.x];
    if (NORM_IN) {
        for (int i = threadIdx.x; i < CIN; i += 256) { iscl[i] = isc[i]; ishl[i] = ish[i]; }
    }
    __syncthreads();
    int r = blockIdx.x * 256 + threadIdx.x;
    float acc[64];
#pragma unroll
    for (int o = 0; o < 64; ++o) acc[o] = blds[o];
    const float4* r4 = (const float4*)(Yin + (size_t)r * CIN);
#pragma unroll 4
    for (int cc = 0; cc < CIN / 4; ++cc) {
        float4 x = r4[cc];
        float xs[4] = {x.x, x.y, x.z, x.w};
#pragma unroll
        for (int u = 0; u < 4; ++u) {
            int c = cc * 4 + u;
            float xv = xs[u];
            if (NORM_IN) xv = fmaxf(fmaf(xv, iscl[c], ishl[c]), 0.0f);
            const float* wr = &wlds[c * 64];
#pragma unroll
            for (int o = 0; o < 64; ++o) acc[o] = fmaf(xv, wr[o], acc[o]);
        }
    }
    if (WRITE_Y) {
        float4* yr = (float4*)(Yout + (size_t)r * OTOT + ob);
#pragma unroll
        for (int o4 = 0; o4 < 16; ++o4)
            yr[o4] = make_float4(acc[o4 * 4], acc[o4 * 4 + 1], acc[o4 * 4 + 2], acc[o4 * 4 + 3]);
    }
    if (PARTIALS) {
        int lane = threadIdx.x & 63, wvv = threadIdx.x >> 6;
#pragma unroll
        for (int o = 0; o < 64; ++o) {
            float v = acc[o], v2 = acc[o] * acc[o];
#pragma unroll
            for (int off = 1; off < 64; off <<= 1) { v += __shfl_xor(v, off); v2 += __shfl_xor(v2, off); }
            if (lane == 0) { lsum[wvv][o] = v; lsq[wvv][o] = v2; }
        }
        __syncthreads();
        if (threadIdx.x < 64) {
            int o = threadIdx.x;
            sumP[blockIdx.x * OTOT + ob + o] = lsum[0][o] + lsum[1][o] + lsum[2][o] + lsum[3][o];
            sqP[blockIdx.x * OTOT + ob + o]  = lsq[0][o] + lsq[1][o] + lsq[2][o] + lsq[3][o];
        }
    }
    if (MAXOUT) {
        int b = r >> 15, s = (r >> 5) & (SS - 1);
#pragma unroll
        for (int o = 0; o < 64; ++o) {
            float v = acc[o];
#pragma unroll
            for (int off = 1; off < 32; off <<= 1) v = fmaxf(v, __shfl_xor(v, off));
            if ((threadIdx.x & 31) == 0)
                ymax[((size_t)b * O3 + ob + o) * SS + s] = v;
        }
    }
}

// ---------------- pool epilogue: out1 = relu(ymax*sc + sh), coalesced ----------
__global__ __launch_bounds__(256) void k_pool(const float* __restrict__ ymax,
                                              const float* __restrict__ sc,
                                              const float* __restrict__ sh,
                                              float* __restrict__ out1) {
    int i = blockIdx.x * 256 + threadIdx.x;    // over BB*O3*SS, layout == out1
    int o = (i >> 10) & (O3 - 1);              // wave-uniform channel
    out1[i] = fmaxf(fmaf(ymax[i], sc[o], sh[o]), 0.0f);
}

// ---------------- finalize BN stats: 512 partials -> scale/shift ---------------
template <int COUT>
__global__ void k_finalize(const float* __restrict__ sumP, const float* __restrict__ sqP,
                           const float* __restrict__ g, const float* __restrict__ beta,
                           float* __restrict__ scale, float* __restrict__ shift) {
    __shared__ float ls[4][COUT], lq[4][COUT];
    int o = threadIdx.x % COUT, q = threadIdx.x / COUT;
    float s = 0.f, qq = 0.f;
    for (int bk = q; bk < 512; bk += 4) { s += sumP[bk * COUT + o]; qq += sqP[bk * COUT + o]; }
    ls[q][o] = s; lq[q][o] = qq;
    __syncthreads();
    if (q == 0) {
        s  = ls[0][o] + ls[1][o] + ls[2][o] + ls[3][o];
        qq = lq[0][o] + lq[1][o] + lq[2][o] + lq[3][o];
        const float inv = 1.0f / (float)RR;
        float mean = s * inv;
        float var = qq * inv - mean * mean;
        float sc = g[o] * rsqrtf(var + EPSF);
        scale[o] = sc;
        shift[o] = beta[o] - mean * sc;
    }
}

extern "C" void kernel_launch(void* const* d_in, const int* in_sizes, int n_in,
                              void* d_out, int out_size, void* d_ws, size_t ws_size,
                              hipStream_t stream) {
    const float* xyz = (const float*)d_in[0];
    const float* pts = (const float*)d_in[1];
    const float* w1  = (const float*)d_in[2];
    const float* b1  = (const float*)d_in[3];
    const float* g1  = (const float*)d_in[4];
    const float* bt1 = (const float*)d_in[5];
    const float* w2  = (const float*)d_in[6];
    const float* b2  = (const float*)d_in[7];
    const float* g2  = (const float*)d_in[8];
    const float* bt2 = (const float*)d_in[9];
    const float* w3  = (const float*)d_in[10];
    const float* b3  = (const float*)d_in[11];
    const float* g3  = (const float*)d_in[12];
    const float* bt3 = (const float*)d_in[13];
    float* out0 = (float*)d_out;                 // (B,3,S)
    float* out1 = out0 + BB * 3 * SS;            // (B,128,S)

    char* wsb = (char*)d_ws;
    size_t off = 0;
    auto alloc = [&](size_t bytes) {
        char* p = wsb + off;
        off += (bytes + 255) & ~(size_t)255;
        return p;
    };
    int*   fps_idx = (int*)alloc((size_t)BB * SS * 4);
    int*   ballidx = (int*)alloc((size_t)RR * 4);
    float* nxyz    = (float*)alloc((size_t)BB * SS * 3 * 4);
    float* sumP    = (float*)alloc((size_t)512 * 128 * 4);
    float* sqP     = (float*)alloc((size_t)512 * 128 * 4);
    float* sc1     = (float*)alloc(128 * 4);
    float* sh1     = (float*)alloc(128 * 4);
    float* sc2     = (float*)alloc(128 * 4);
    float* sh2     = (float*)alloc(128 * 4);
    float* sc3     = (float*)alloc(128 * 4);
    float* sh3     = (float*)alloc(128 * 4);
    float* ymax    = (float*)alloc((size_t)BB * O3 * SS * 4);
    float* Y1      = (float*)alloc((size_t)RR * 64 * 4);
    float* Y2      = (float*)alloc((size_t)RR * 64 * 4);
    float* ptsT    = Y2;   // ptsT (16 MB) lives in Y2's slot; Y2 written after gemm1

    // fused: blocks 0..3 run FPS (4 CUs); blocks 4..1027 transpose pts on the
    // other 252 CUs, fully hidden under the FPS tail.
    k_fps<<<BB + 1024, FT, 0, stream>>>(xyz, fps_idx, pts, ptsT);
    k_newxyz<<<16, 256, 0, stream>>>(xyz, fps_idx, out0, nxyz);
    k_ball<<<1024, 256, 0, stream>>>(xyz, nxyz, ballidx);

    k_gemm1<<<512, 256, 0, stream>>>(xyz, ptsT, nxyz, ballidx, w1, b1, Y1, sumP, sqP);
    k_finalize<64><<<1, 256, 0, stream>>>(sumP, sqP, g1, bt1, sc1, sh1);

    k_mlp<64, 64, true, true, true, false><<<dim3(512, 1), 256, 0, stream>>>(
        Y1, w2, b2, sc1, sh1, Y2, sumP, sqP, nullptr);
    k_finalize<64><<<1, 256, 0, stream>>>(sumP, sqP, g2, bt2, sc2, sh2);

    k_mlp<64, 128, true, false, true, true><<<dim3(512, 2), 256, 0, stream>>>(
        Y2, w3, b3, sc2, sh2, nullptr, sumP, sqP, ymax);
    k_finalize<128><<<1, 512, 0, stream>>>(sumP, sqP, g3, bt3, sc3, sh3);

    k_pool<<<BB * O3 * SS / 256, 256, 0, stream>>>(ymax, sc3, sh3, out1);
}